// Round 2
// baseline (227.245 us; speedup 1.0000x reference)
//
#include <hip/hip_runtime.h>
#include <math.h>

#define T_TOTAL 262144
#define HIDN 20
#define IND 9

// ---- scan geometry: 4096 blocks -> 16 blocks/CU -> 4 waves/SIMD
#define CHUNK 64
#define WARM 32
#define NBLK (T_TOTAL / CHUNK)          // 4096

// xg workspace: [T][20] float4 (gates i,f,g,o per unit), bias b1 folded in
#define XG_BYTES ((size_t)T_TOTAL * 4 * HIDN * sizeof(float))   // 83.9 MB

typedef float float4v __attribute__((ext_vector_type(4)));

__device__ __forceinline__ float fexp(float x) {
    return __builtin_amdgcn_exp2f(x * 1.44269504088896340736f);
}
__device__ __forceinline__ float sigf(float x) {
    return __builtin_amdgcn_rcpf(1.0f + fexp(-x));
}
__device__ __forceinline__ float tanhfst(float x) {
    return 1.0f - 2.0f * __builtin_amdgcn_rcpf(1.0f + fexp(2.0f * x));
}
__device__ __forceinline__ float hsum4(float4v a) {
    return (a.x + a.y) + (a.z + a.w);
}

// ============================================================================
// Kernel 1: xg[t][k] = b1 + W_ih1 . x[t]  (recurrence-independent precompute).
// 2 outputs/thread sharing the LDS-staged weight row (t and t+T/2, same k):
// per-output ~65 instr vs ~110 single-output.
// ============================================================================
#define XP_OUTS  (T_TOTAL * HIDN)     // 5242880
#define XP_HALF  (XP_OUTS / 2)        // 2621440  (divisible by HIDN: t-shift 131072)
#define XP_BLOCKS (XP_HALF / 256)     // 10240

__global__ __launch_bounds__(256)
void xproj(const float* __restrict__ x, const float* __restrict__ w_ih1,
           const float* __restrict__ b1, float4v* __restrict__ xg)
{
    __shared__ float wsm[4 * HIDN * IND + 4 * HIDN];   // 720 w + 80 b
    const int tid = threadIdx.x;
    for (int i = tid; i < 4 * HIDN * IND; i += 256) wsm[i] = w_ih1[i];
    for (int i = tid; i < 4 * HIDN; i += 256) wsm[4 * HIDN * IND + i] = b1[i];
    __syncthreads();

    const unsigned i0 = blockIdx.x * 256 + tid;        // first flat output
    const unsigned i1 = i0 + XP_HALF;                  // second: same k, t+131072
    const unsigned t0 = i0 / HIDN;
    const int k = (int)(i0 - t0 * HIDN);
    const unsigned t1 = t0 + (XP_HALF / HIDN);

    const float* xr0 = x + (size_t)t0 * IND;
    const float* xr1 = x + (size_t)t1 * IND;
    float xa[IND], xb[IND];
#pragma unroll
    for (int d = 0; d < IND; ++d) { xa[d] = xr0[d]; xb[d] = xr1[d]; }

    float4v r0, r1;
#pragma unroll
    for (int q = 0; q < 4; ++q) {
        const float* wr = &wsm[(q * HIDN + k) * IND];
        const float bb = wsm[4 * HIDN * IND + q * HIDN + k];
        float a0 = bb, a1 = bb;
#pragma unroll
        for (int d = 0; d < IND; ++d) {
            const float w = wr[d];
            a0 = fmaf(w, xa[d], a0);
            a1 = fmaf(w, xb[d], a1);
        }
        r0[q] = a0; r1[q] = a1;
    }
    xg[i0] = r0;    // coalesced 16B/lane
    xg[i1] = r1;
}

// ============================================================================
// Kernel 2: recurrent scan. Lanes 0-19: layer1 unit k (xg adds input proj).
// Lanes 20-39: layer2 W_ih2 half (state owner). Lanes 40-59: layer2 W_hh2
// half. Lanes 60-63 idle (zero weights).
// amdgpu_waves_per_eu(4,4): min=max=4 waves/EU -> VGPR budget 128 and NO
// incentive to compact below it (round-1's VGPR_Count=64 showed the backend
// chasing 8 waves/EU and shuffling the 84 weight floats through AGPRs,
// ~2x instruction inflation per step).
// ============================================================================
#define DECLW2(q) float4v wv##q##0, wv##q##1, wv##q##2, wv##q##3, wv##q##4; float bq##q;
#define LOADW2(q) { \
    const float4v* wr = (const float4v*)(wbase + ((q) * HIDN + krow) * HIDN); \
    wv##q##0 = scale * wr[0]; wv##q##1 = scale * wr[1]; wv##q##2 = scale * wr[2]; \
    wv##q##3 = scale * wr[3]; wv##q##4 = scale * wr[4]; \
    bq##q = (grp == 1) ? b2[(q) * HIDN + k] : 0.0f; \
}

// scalar (uniform) row index, clamped; per-lane part is just +krow
#define XGROW(t) ((size_t)(((t) < T_TOTAL) ? (t) : (T_TOTAL - 1)) * HIDN)

__global__ __launch_bounds__(64) __attribute__((amdgpu_waves_per_eu(4, 4)))
void lstm_scan2(const float4v* __restrict__ xg,
                const float* __restrict__ w_hh1,
                const float* __restrict__ w_ih2, const float* __restrict__ w_hh2,
                const float* __restrict__ b2,
                const float* __restrict__ w_p, const float* __restrict__ b_p,
                float* __restrict__ out)
{
    __shared__ __align__(16) float hcur[128];           // h1@[0..19], h2@[32..51], scratch@[64..87]
    __shared__ __align__(16) float h2out[CHUNK * HIDN + 64];  // +64 scratch slots

    const int lane = threadIdx.x;
    const int blk  = blockIdx.x;
    const int t0   = blk * CHUNK;
    const int start = (t0 >= WARM) ? (t0 - WARM) : 0;
    const int endt  = t0 + CHUNK;

    hcur[lane] = 0.0f;
    hcur[64 + lane] = 0.0f;

    const int grp  = lane / 20;
    const int k    = lane - grp * 20;
    const int krow = (grp < 3) ? k : 0;
    const float scale = (grp < 3) ? 1.0f : 0.0f;
    const float* wbase = (grp == 1) ? w_ih2 : ((grp == 2) ? w_hh2 : w_hh1);

    DECLW2(0) DECLW2(1) DECLW2(2) DECLW2(3)
    LOADW2(0) LOADW2(1) LOADW2(2) LOADW2(3)

    const float* vbase = (lane < 40) ? hcur : (hcur + 32);
    const bool  isl2   = (lane >= 20 && lane < 40);
    const float m2     = isl2 ? 1.0f : 0.0f;
    const float m1     = (grp == 0) ? 1.0f : 0.0f;   // only L1 lanes add xg
    const int   h2col  = lane - 20;
    // branchless state-write slot: L1 -> [0..19], L2-owner -> [32..51], rest -> scratch [64..87]
    const int   hslot  = (lane < 20) ? lane : ((lane < 40) ? (lane + 12) : (64 + lane - 40));
    const int   shsrc  = (lane + 20) & 63;
    const int   h2scr  = CHUNK * HIDN + lane;        // scratch slot for invalid h2out writes

    // xg stream: depth-2 register prefetch (xg comes from HBM each rep —
    // FETCH_SIZE 64MB, ~900cy latency needs 2 steps of cover)
    float4v xg_use = xg[XGROW(start) + krow];
    float4v n1     = xg[XGROW(start + 1) + krow];
    float4v n2     = xg[XGROW(start + 2) + krow];

    __syncthreads();

    float c = 0.0f, h = 0.0f;

    // ---- peeled first step (s == start): h,c zero -> gates are xg/bias only
    {
        float a0 = fmaf(m1, xg_use.x, bq0);
        float a2 = fmaf(m1, xg_use.z, bq2);
        float a3 = fmaf(m1, xg_use.w, bq3);
        float gi = sigf(a0), gg = tanhfst(a2), go = sigf(a3);
        float cn = gi * gg;
        float hn = go * tanhfst(cn);
        c = (lane < 20) ? cn : 0.0f;
        h = (lane < 20) ? hn : 0.0f;
        hcur[hslot] = h;                  // L2 owner lanes write 0 (correct)
        __syncthreads();
    }

    // ---- main loop: s = start+1 .. endt
    for (int s = start + 1; s <= endt; ++s) {
        float4v xgv = n1;                 // row s
        n1 = n2;
        n2 = xg[XGROW(s + 2) + krow];     // in flight for 2 full steps

        const float4v* vb4 = (const float4v*)vbase;
        float4v v  = vb4[0];
        float4v s0 = wv00 * v, s1 = wv10 * v, s2 = wv20 * v, s3 = wv30 * v;
        v = vb4[1]; s0 += wv01 * v; s1 += wv11 * v; s2 += wv21 * v; s3 += wv31 * v;
        v = vb4[2]; s0 += wv02 * v; s1 += wv12 * v; s2 += wv22 * v; s3 += wv32 * v;
        v = vb4[3]; s0 += wv03 * v; s1 += wv13 * v; s2 += wv23 * v; s3 += wv33 * v;
        v = vb4[4]; s0 += wv04 * v; s1 += wv14 * v; s2 += wv24 * v; s3 += wv34 * v;

        float a0 = hsum4(s0) + fmaf(m1, xgv.x, bq0);
        float a1 = hsum4(s1) + fmaf(m1, xgv.y, bq1);
        float a2 = hsum4(s2) + fmaf(m1, xgv.z, bq2);
        float a3 = hsum4(s3) + fmaf(m1, xgv.w, bq3);

        // layer-2 combine: lane 20+k += lane 40+k (masked fma)
        a0 = fmaf(m2, __shfl(a0, shsrc, 64), a0);
        a1 = fmaf(m2, __shfl(a1, shsrc, 64), a1);
        a2 = fmaf(m2, __shfl(a2, shsrc, 64), a2);
        a3 = fmaf(m2, __shfl(a3, shsrc, 64), a3);

        float gi = sigf(a0), gf = sigf(a1), gg = tanhfst(a2), go = sigf(a3);
        c = fmaf(gf, c, gi * gg);
        h = go * tanhfst(c);

        hcur[hslot] = h;                                  // branchless (scratch redirect)
        const int widx = (isl2 && s > t0) ? ((s - 1 - t0) * HIDN + h2col) : h2scr;
        h2out[widx] = h;                                  // branchless (scratch redirect)

        __syncthreads();
    }

    // ---- projection epilogue: out[t] = w_p . h2[t] + b_p  (one t per lane)
    {
        const float4v* wp4 = (const float4v*)w_p;
        float4v p0 = wp4[0], p1 = wp4[1], p2 = wp4[2], p3 = wp4[3], p4 = wp4[4];
        const float bp = b_p[0];
        for (int tt = lane; tt < CHUNK; tt += 64) {
            const float4v* hr = (const float4v*)(h2out + tt * HIDN);
            float4v s_ = p0 * hr[0];
            s_ += p1 * hr[1]; s_ += p2 * hr[2]; s_ += p3 * hr[3]; s_ += p4 * hr[4];
            out[t0 + tt] = hsum4(s_) + bp;
        }
    }
}

// ============================================================================
// Fallback (round-0 kernel, verbatim): used only if ws_size is too small for
// the xg workspace.
// ============================================================================
#define V0CHUNK 128
#define V0WARM 48
#define V0MAXST (V0WARM + V0CHUNK + 1)
#define V0NBLK (T_TOTAL / V0CHUNK)

#define DECLW(q) \
    float4v w0v##q##0, w0v##q##1, w0v##q##2, w0v##q##3, w0v##q##4; \
    float4v w0x##q##0, w0x##q##1; float w0x##q##8; float b0q##q;

#define LOADW(q) { \
    const float4v* wr = (const float4v*)(wbase + ((q) * HIDN + krow) * HIDN); \
    w0v##q##0 = scale * wr[0]; w0v##q##1 = scale * wr[1]; w0v##q##2 = scale * wr[2]; \
    w0v##q##3 = scale * wr[3]; w0v##q##4 = scale * wr[4]; \
    w0x##q##0 = (float4v)0.0f; w0x##q##1 = (float4v)0.0f; w0x##q##8 = 0.0f; \
    if (grp == 0) { \
        const float* r = w_ih1 + ((q) * HIDN + k) * IND; \
        w0x##q##0 = (float4v){r[0], r[1], r[2], r[3]}; \
        w0x##q##1 = (float4v){r[4], r[5], r[6], r[7]}; \
        w0x##q##8 = r[8]; \
    } \
    b0q##q = (grp == 0) ? b1[(q) * HIDN + k] : ((grp == 1) ? b2[(q) * HIDN + k] : 0.0f); \
}

#define GATE(q) ({ \
    float4v s_ = w0v##q##0 * v0; \
    s_ += w0v##q##1 * v1; s_ += w0v##q##2 * v2; \
    s_ += w0v##q##3 * v3; s_ += w0v##q##4 * v4; \
    s_ += w0x##q##0 * xv0; s_ += w0x##q##1 * xv1; \
    hsum4(s_) + fmaf(w0x##q##8, xv8, b0q##q); })

#define GATEX(q) ({ \
    float4v s_ = w0x##q##0 * xv0 + w0x##q##1 * xv1; \
    hsum4(s_) + fmaf(w0x##q##8, xv8, b0q##q); })

__global__ __launch_bounds__(64)
void lstm_scan_v0(const float* __restrict__ x,
                  const float* __restrict__ w_ih1, const float* __restrict__ w_hh1,
                  const float* __restrict__ b1,
                  const float* __restrict__ w_ih2, const float* __restrict__ w_hh2,
                  const float* __restrict__ b2,
                  const float* __restrict__ w_p, const float* __restrict__ b_p,
                  float* __restrict__ out)
{
    __shared__ __align__(16) float xbuf[V0MAXST * 12];
    __shared__ __align__(16) float hcur[64];
    __shared__ __align__(16) float h2out[V0CHUNK * HIDN];

    const int lane = threadIdx.x;
    const int blk  = blockIdx.x;
    const int t0   = blk * V0CHUNK;
    const int start = (t0 >= V0WARM) ? (t0 - V0WARM) : 0;
    const int endt  = t0 + V0CHUNK;
    const int nst   = endt - start + 1;

    for (int idx = lane; idx < nst * IND; idx += 64) {
        int stp = idx / IND, d = idx - stp * IND;
        int gt = start + stp; if (gt > T_TOTAL - 1) gt = T_TOTAL - 1;
        xbuf[stp * 12 + d] = x[gt * IND + d];
    }
    hcur[lane] = 0.0f;

    const int grp  = lane / 20;
    const int k    = lane - grp * 20;
    const int krow = (grp < 3) ? k : 0;
    const float scale = (grp < 3) ? 1.0f : 0.0f;
    const float* wbase = (grp == 1) ? w_ih2 : ((grp == 2) ? w_hh2 : w_hh1);

    DECLW(0) DECLW(1) DECLW(2) DECLW(3)
    LOADW(0) LOADW(1) LOADW(2) LOADW(3)

    const float* vbase = (lane < 40) ? hcur : (hcur + 32);
    const bool  isl2   = (lane >= 20 && lane < 40);
    const float m2     = isl2 ? 1.0f : 0.0f;
    const int   h2col  = lane - 20;
    const int   hslot  = (lane < 20) ? lane : (32 + h2col);
    const int   shsrc  = (lane + 20) & 63;

    __syncthreads();

    float c = 0.0f, h = 0.0f;

    {
        const float* xr = &xbuf[0];
        float4v xv0 = *(const float4v*)xr, xv1 = *(const float4v*)(xr + 4);
        float xv8 = xr[8];
        float a0 = GATEX(0), a1 = GATEX(1), a2 = GATEX(2), a3 = GATEX(3);
        float gi = sigf(a0), gg = tanhfst(a2), go = sigf(a3);
        (void)a1;
        float cn = gi * gg;
        float hn = go * tanhfst(cn);
        c = (lane < 20) ? cn : 0.0f;
        h = (lane < 20) ? hn : 0.0f;
        if (lane < 40) hcur[hslot] = h;
        __syncthreads();
    }

    for (int s = start + 1; s <= endt; ++s) {
        const float4v* vb4 = (const float4v*)vbase;
        float4v v0 = vb4[0], v1 = vb4[1], v2 = vb4[2], v3 = vb4[3], v4 = vb4[4];

        const float* xr = &xbuf[(s - start) * 12];
        float4v xv0 = *(const float4v*)xr, xv1 = *(const float4v*)(xr + 4);
        float xv8 = xr[8];

        float a0 = GATE(0), a1 = GATE(1), a2 = GATE(2), a3 = GATE(3);

        a0 = fmaf(m2, __shfl(a0, shsrc, 64), a0);
        a1 = fmaf(m2, __shfl(a1, shsrc, 64), a1);
        a2 = fmaf(m2, __shfl(a2, shsrc, 64), a2);
        a3 = fmaf(m2, __shfl(a3, shsrc, 64), a3);

        float gi = sigf(a0), gf = sigf(a1), gg = tanhfst(a2), go = sigf(a3);
        c = fmaf(gf, c, gi * gg);
        h = go * tanhfst(c);

        if (lane < 40) hcur[hslot] = h;
        if (isl2 && s > t0) h2out[(s - 1 - t0) * HIDN + h2col] = h;

        __syncthreads();
    }

    {
        const float4v* wp4 = (const float4v*)w_p;
        float4v p0 = wp4[0], p1 = wp4[1], p2 = wp4[2], p3 = wp4[3], p4 = wp4[4];
        const float bp = b_p[0];
        for (int tt = lane; tt < V0CHUNK; tt += 64) {
            const float4v* hr = (const float4v*)(h2out + tt * HIDN);
            float4v s_ = p0 * hr[0];
            s_ += p1 * hr[1]; s_ += p2 * hr[2]; s_ += p3 * hr[3]; s_ += p4 * hr[4];
            out[t0 + tt] = hsum4(s_) + bp;
        }
    }
}

extern "C" void kernel_launch(void* const* d_in, const int* in_sizes, int n_in,
                              void* d_out, int out_size, void* d_ws, size_t ws_size,
                              hipStream_t stream) {
    const float* x     = (const float*)d_in[0];
    const float* w_ih1 = (const float*)d_in[1];
    const float* w_hh1 = (const float*)d_in[2];
    const float* b1    = (const float*)d_in[3];
    const float* w_ih2 = (const float*)d_in[4];
    const float* w_hh2 = (const float*)d_in[5];
    const float* b2    = (const float*)d_in[6];
    const float* w_p   = (const float*)d_in[7];
    const float* b_p   = (const float*)d_in[8];
    float* out = (float*)d_out;

    if (ws_size >= XG_BYTES && d_ws != nullptr) {
        float4v* xg = (float4v*)d_ws;
        xproj<<<XP_BLOCKS, 256, 0, stream>>>(x, w_ih1, b1, xg);
        lstm_scan2<<<NBLK, 64, 0, stream>>>(xg, w_hh1, w_ih2, w_hh2, b2,
                                            w_p, b_p, out);
    } else {
        // workspace too small for xg: previous-generation fused kernel
        lstm_scan_v0<<<V0NBLK, 64, 0, stream>>>(x, w_ih1, w_hh1, b1,
                                                w_ih2, w_hh2, b2, w_p, b_p, out);
    }
}

// Round 3
// 201.486 us; speedup vs baseline: 1.1278x; 1.1278x over previous
//
#include <hip/hip_runtime.h>
#include <math.h>

#define T_TOTAL 262144
#define HIDN 20
#define IND 9

// ---- scan geometry: 4096 blocks -> 16 blocks/CU -> 4 waves/SIMD
#define CHUNK 64
#define WARM 32
#define NBLK (T_TOTAL / CHUNK)          // 4096

// xg workspace: [T][20] float4 (gates i,f,g,o per unit), bias b1 folded in
#define XG_BYTES ((size_t)T_TOTAL * 4 * HIDN * sizeof(float))   // 83.9 MB

typedef float float4v __attribute__((ext_vector_type(4)));
typedef float float2v __attribute__((ext_vector_type(2)));

__device__ __forceinline__ float fexp(float x) {
    return __builtin_amdgcn_exp2f(x * 1.44269504088896340736f);
}
__device__ __forceinline__ float sigf(float x) {
    return __builtin_amdgcn_rcpf(1.0f + fexp(-x));
}
__device__ __forceinline__ float tanhfst(float x) {
    return 1.0f - 2.0f * __builtin_amdgcn_rcpf(1.0f + fexp(2.0f * x));
}
__device__ __forceinline__ float hsum4(float4v a) {
    return (a.x + a.y) + (a.z + a.w);
}

#define LO2(a) __builtin_shufflevector(a, a, 0, 1)
#define HI2(a) __builtin_shufflevector(a, a, 2, 3)

// intra-wave LDS fence: single-wave block needs NO s_barrier (which would
// force vmcnt(0) and drain the xg prefetch queue every step — the round-2
// dominant stall). lgkmcnt(0) + memory clobber gives wave-wide LDS
// visibility and blocks compiler reordering of LDS ops across it.
#define LDS_FENCE() asm volatile("s_waitcnt lgkmcnt(0)" ::: "memory")

// ============================================================================
// Kernel 1: xg[t][k] = b1 + W_ih1 . x[t]  (recurrence-independent precompute).
// 2 outputs/thread sharing the LDS-staged weight row (t and t+T/2, same k).
// ============================================================================
#define XP_OUTS  (T_TOTAL * HIDN)     // 5242880
#define XP_HALF  (XP_OUTS / 2)        // 2621440  (divisible by HIDN)
#define XP_BLOCKS (XP_HALF / 256)     // 10240

__global__ __launch_bounds__(256)
void xproj(const float* __restrict__ x, const float* __restrict__ w_ih1,
           const float* __restrict__ b1, float4v* __restrict__ xg)
{
    __shared__ float wsm[4 * HIDN * IND + 4 * HIDN];   // 720 w + 80 b
    const int tid = threadIdx.x;
    for (int i = tid; i < 4 * HIDN * IND; i += 256) wsm[i] = w_ih1[i];
    for (int i = tid; i < 4 * HIDN; i += 256) wsm[4 * HIDN * IND + i] = b1[i];
    __syncthreads();

    const unsigned i0 = blockIdx.x * 256 + tid;
    const unsigned i1 = i0 + XP_HALF;                  // same k, t + 131072
    const unsigned t0 = i0 / HIDN;
    const int k = (int)(i0 - t0 * HIDN);
    const unsigned t1 = t0 + (XP_HALF / HIDN);

    const float* xr0 = x + (size_t)t0 * IND;
    const float* xr1 = x + (size_t)t1 * IND;
    float xa[IND], xb[IND];
#pragma unroll
    for (int d = 0; d < IND; ++d) { xa[d] = xr0[d]; xb[d] = xr1[d]; }

    float4v r0, r1;
#pragma unroll
    for (int q = 0; q < 4; ++q) {
        const float* wr = &wsm[(q * HIDN + k) * IND];
        const float bb = wsm[4 * HIDN * IND + q * HIDN + k];
        float a0 = bb, a1 = bb;
#pragma unroll
        for (int d = 0; d < IND; ++d) {
            const float w = wr[d];
            a0 = fmaf(w, xa[d], a0);
            a1 = fmaf(w, xb[d], a1);
        }
        r0[q] = a0; r1[q] = a1;
    }
    xg[i0] = r0;
    xg[i1] = r1;
}

// ============================================================================
// Kernel 2: recurrent scan. Lanes 0-19: layer1 unit k (xg adds input proj).
// Lanes 20-39: layer2 W_ih2 half (state owner). Lanes 40-59: layer2 W_hh2
// half. Lanes 60-63 idle (zero weights).
// Single wave/block; NO s_barrier in the step loop (LDS_FENCE only) so the
// depth-2 xg prefetch stays in flight across steps.
// Dot products via float2 elementwise-fma -> v_pk_fma_f32 (packed f32).
// ============================================================================
#define DECLW2(q) float4v wv##q##0, wv##q##1, wv##q##2, wv##q##3, wv##q##4; float bq##q;
#define LOADW2(q) { \
    const float4v* wr = (const float4v*)(wbase + ((q) * HIDN + krow) * HIDN); \
    wv##q##0 = scale * wr[0]; wv##q##1 = scale * wr[1]; wv##q##2 = scale * wr[2]; \
    wv##q##3 = scale * wr[3]; wv##q##4 = scale * wr[4]; \
    bq##q = (grp == 1) ? b2[(q) * HIDN + k] : 0.0f; \
}

// one float4 chunk of the 20-dot, all 4 gates, packed-f32 pairs
#define PKCHUNK(j) { \
    float4v v = vb4[j]; \
    float2v vl = LO2(v), vh = HI2(v); \
    p0 = __builtin_elementwise_fma(LO2(wv0##j), vl, p0); \
    r0 = __builtin_elementwise_fma(HI2(wv0##j), vh, r0); \
    p1 = __builtin_elementwise_fma(LO2(wv1##j), vl, p1); \
    r1 = __builtin_elementwise_fma(HI2(wv1##j), vh, r1); \
    p2 = __builtin_elementwise_fma(LO2(wv2##j), vl, p2); \
    r2 = __builtin_elementwise_fma(HI2(wv2##j), vh, r2); \
    p3 = __builtin_elementwise_fma(LO2(wv3##j), vl, p3); \
    r3 = __builtin_elementwise_fma(HI2(wv3##j), vh, r3); \
}

// scalar (uniform) clamped row base; per-lane part is +krow
#define XGROW(t) ((size_t)(((t) < T_TOTAL) ? (t) : (T_TOTAL - 1)) * HIDN)

__global__ __launch_bounds__(64)
void lstm_scan2(const float4v* __restrict__ xg,
                const float* __restrict__ w_hh1,
                const float* __restrict__ w_ih2, const float* __restrict__ w_hh2,
                const float* __restrict__ b2,
                const float* __restrict__ w_p, const float* __restrict__ b_p,
                float* __restrict__ out)
{
    __shared__ __align__(16) float hcur[64];            // h1@[0..19], h2@[32..51]
    __shared__ __align__(16) float h2out[CHUNK * HIDN];

    const int lane = threadIdx.x;
    const int blk  = blockIdx.x;
    const int t0   = blk * CHUNK;
    const int start = (t0 >= WARM) ? (t0 - WARM) : 0;
    const int endt  = t0 + CHUNK;

    hcur[lane] = 0.0f;

    const int grp  = lane / 20;
    const int k    = lane - grp * 20;
    const int krow = (grp < 3) ? k : 0;
    const float scale = (grp < 3) ? 1.0f : 0.0f;
    const float* wbase = (grp == 1) ? w_ih2 : ((grp == 2) ? w_hh2 : w_hh1);

    DECLW2(0) DECLW2(1) DECLW2(2) DECLW2(3)
    LOADW2(0) LOADW2(1) LOADW2(2) LOADW2(3)

    const float* vbase = (lane < 40) ? hcur : (hcur + 32);
    const bool  isl2   = (lane >= 20 && lane < 40);
    const float m2     = isl2 ? 1.0f : 0.0f;
    const float m1     = (grp == 0) ? 1.0f : 0.0f;   // only L1 lanes add xg
    const int   h2col  = lane - 20;
    const int   hslot  = (lane < 20) ? lane : (32 + h2col);
    const int   shsrc  = (lane + 20) & 63;

    // xg stream: depth-2 register prefetch; with no per-step barrier the
    // loads stay in flight for 2 full steps (covers ~900cy HBM latency)
    float4v xg_use = xg[XGROW(start) + krow];
    float4v n1     = xg[XGROW(start + 1) + krow];
    float4v n2     = xg[XGROW(start + 2) + krow];

    float c = 0.0f, h = 0.0f;

    // ---- peeled first step (s == start): h,c zero -> gates are xg/bias only
    {
        float a0 = fmaf(m1, xg_use.x, bq0);
        float a2 = fmaf(m1, xg_use.z, bq2);
        float a3 = fmaf(m1, xg_use.w, bq3);
        float gi = sigf(a0), gg = tanhfst(a2), go = sigf(a3);
        float cn = gi * gg;
        float hn = go * tanhfst(cn);
        c = (lane < 20) ? cn : 0.0f;
        h = (lane < 20) ? hn : 0.0f;
        if (lane < 40) hcur[hslot] = h;   // layer-2 slots stay 0
        LDS_FENCE();
    }

    // ---- main loop: s = start+1 .. endt  (no s_barrier: single wave)
    for (int s = start + 1; s <= endt; ++s) {
        float4v xgv = n1;                 // row s
        n1 = n2;
        n2 = xg[XGROW(s + 2) + krow];     // in flight for 2 full steps

        const float4v* vb4 = (const float4v*)vbase;
        float2v p0 = (float2v)0.0f, r0 = (float2v)0.0f;
        float2v p1 = (float2v)0.0f, r1 = (float2v)0.0f;
        float2v p2 = (float2v)0.0f, r2 = (float2v)0.0f;
        float2v p3 = (float2v)0.0f, r3 = (float2v)0.0f;
        PKCHUNK(0) PKCHUNK(1) PKCHUNK(2) PKCHUNK(3) PKCHUNK(4)

        float2v t0v = p0 + r0, t1v = p1 + r1, t2v = p2 + r2, t3v = p3 + r3;
        float a0 = (t0v.x + t0v.y) + fmaf(m1, xgv.x, bq0);
        float a1 = (t1v.x + t1v.y) + fmaf(m1, xgv.y, bq1);
        float a2 = (t2v.x + t2v.y) + fmaf(m1, xgv.z, bq2);
        float a3 = (t3v.x + t3v.y) + fmaf(m1, xgv.w, bq3);

        // layer-2 combine: lane 20+k += lane 40+k (masked fma)
        a0 = fmaf(m2, __shfl(a0, shsrc, 64), a0);
        a1 = fmaf(m2, __shfl(a1, shsrc, 64), a1);
        a2 = fmaf(m2, __shfl(a2, shsrc, 64), a2);
        a3 = fmaf(m2, __shfl(a3, shsrc, 64), a3);

        float gi = sigf(a0), gf = sigf(a1), gg = tanhfst(a2), go = sigf(a3);
        c = fmaf(gf, c, gi * gg);
        h = go * tanhfst(c);

        if (lane < 40) hcur[hslot] = h;                 // 2-way bank alias: free
        if (isl2 && s > t0) h2out[(s - 1 - t0) * HIDN + h2col] = h;

        LDS_FENCE();
    }

    // ---- projection epilogue: out[t] = w_p . h2[t] + b_p  (one t per lane)
    {
        const float4v* wp4 = (const float4v*)w_p;
        float4v q0 = wp4[0], q1 = wp4[1], q2 = wp4[2], q3 = wp4[3], q4 = wp4[4];
        const float bp = b_p[0];
        for (int tt = lane; tt < CHUNK; tt += 64) {
            const float4v* hr = (const float4v*)(h2out + tt * HIDN);
            float4v s_ = q0 * hr[0];
            s_ += q1 * hr[1]; s_ += q2 * hr[2]; s_ += q3 * hr[3]; s_ += q4 * hr[4];
            out[t0 + tt] = hsum4(s_) + bp;
        }
    }
}

// ============================================================================
// Fallback (round-0 kernel, verbatim): used only if ws_size is too small for
// the xg workspace.
// ============================================================================
#define V0CHUNK 128
#define V0WARM 48
#define V0MAXST (V0WARM + V0CHUNK + 1)
#define V0NBLK (T_TOTAL / V0CHUNK)

#define DECLW(q) \
    float4v w0v##q##0, w0v##q##1, w0v##q##2, w0v##q##3, w0v##q##4; \
    float4v w0x##q##0, w0x##q##1; float w0x##q##8; float b0q##q;

#define LOADW(q) { \
    const float4v* wr = (const float4v*)(wbase + ((q) * HIDN + krow) * HIDN); \
    w0v##q##0 = scale * wr[0]; w0v##q##1 = scale * wr[1]; w0v##q##2 = scale * wr[2]; \
    w0v##q##3 = scale * wr[3]; w0v##q##4 = scale * wr[4]; \
    w0x##q##0 = (float4v)0.0f; w0x##q##1 = (float4v)0.0f; w0x##q##8 = 0.0f; \
    if (grp == 0) { \
        const float* r = w_ih1 + ((q) * HIDN + k) * IND; \
        w0x##q##0 = (float4v){r[0], r[1], r[2], r[3]}; \
        w0x##q##1 = (float4v){r[4], r[5], r[6], r[7]}; \
        w0x##q##8 = r[8]; \
    } \
    b0q##q = (grp == 0) ? b1[(q) * HIDN + k] : ((grp == 1) ? b2[(q) * HIDN + k] : 0.0f); \
}

#define GATE(q) ({ \
    float4v s_ = w0v##q##0 * v0; \
    s_ += w0v##q##1 * v1; s_ += w0v##q##2 * v2; \
    s_ += w0v##q##3 * v3; s_ += w0v##q##4 * v4; \
    s_ += w0x##q##0 * xv0; s_ += w0x##q##1 * xv1; \
    hsum4(s_) + fmaf(w0x##q##8, xv8, b0q##q); })

#define GATEX(q) ({ \
    float4v s_ = w0x##q##0 * xv0 + w0x##q##1 * xv1; \
    hsum4(s_) + fmaf(w0x##q##8, xv8, b0q##q); })

__global__ __launch_bounds__(64)
void lstm_scan_v0(const float* __restrict__ x,
                  const float* __restrict__ w_ih1, const float* __restrict__ w_hh1,
                  const float* __restrict__ b1,
                  const float* __restrict__ w_ih2, const float* __restrict__ w_hh2,
                  const float* __restrict__ b2,
                  const float* __restrict__ w_p, const float* __restrict__ b_p,
                  float* __restrict__ out)
{
    __shared__ __align__(16) float xbuf[V0MAXST * 12];
    __shared__ __align__(16) float hcur[64];
    __shared__ __align__(16) float h2out[V0CHUNK * HIDN];

    const int lane = threadIdx.x;
    const int blk  = blockIdx.x;
    const int t0   = blk * V0CHUNK;
    const int start = (t0 >= V0WARM) ? (t0 - V0WARM) : 0;
    const int endt  = t0 + V0CHUNK;
    const int nst   = endt - start + 1;

    for (int idx = lane; idx < nst * IND; idx += 64) {
        int stp = idx / IND, d = idx - stp * IND;
        int gt = start + stp; if (gt > T_TOTAL - 1) gt = T_TOTAL - 1;
        xbuf[stp * 12 + d] = x[gt * IND + d];
    }
    hcur[lane] = 0.0f;

    const int grp  = lane / 20;
    const int k    = lane - grp * 20;
    const int krow = (grp < 3) ? k : 0;
    const float scale = (grp < 3) ? 1.0f : 0.0f;
    const float* wbase = (grp == 1) ? w_ih2 : ((grp == 2) ? w_hh2 : w_hh1);

    DECLW(0) DECLW(1) DECLW(2) DECLW(3)
    LOADW(0) LOADW(1) LOADW(2) LOADW(3)

    const float* vbase = (lane < 40) ? hcur : (hcur + 32);
    const bool  isl2   = (lane >= 20 && lane < 40);
    const float m2     = isl2 ? 1.0f : 0.0f;
    const int   h2col  = lane - 20;
    const int   hslot  = (lane < 20) ? lane : (32 + h2col);
    const int   shsrc  = (lane + 20) & 63;

    __syncthreads();

    float c = 0.0f, h = 0.0f;

    {
        const float* xr = &xbuf[0];
        float4v xv0 = *(const float4v*)xr, xv1 = *(const float4v*)(xr + 4);
        float xv8 = xr[8];
        float a0 = GATEX(0), a1 = GATEX(1), a2 = GATEX(2), a3 = GATEX(3);
        float gi = sigf(a0), gg = tanhfst(a2), go = sigf(a3);
        (void)a1;
        float cn = gi * gg;
        float hn = go * tanhfst(cn);
        c = (lane < 20) ? cn : 0.0f;
        h = (lane < 20) ? hn : 0.0f;
        if (lane < 40) hcur[hslot] = h;
        __syncthreads();
    }

    for (int s = start + 1; s <= endt; ++s) {
        const float4v* vb4 = (const float4v*)vbase;
        float4v v0 = vb4[0], v1 = vb4[1], v2 = vb4[2], v3 = vb4[3], v4 = vb4[4];

        const float* xr = &xbuf[(s - start) * 12];
        float4v xv0 = *(const float4v*)xr, xv1 = *(const float4v*)(xr + 4);
        float xv8 = xr[8];

        float a0 = GATE(0), a1 = GATE(1), a2 = GATE(2), a3 = GATE(3);

        a0 = fmaf(m2, __shfl(a0, shsrc, 64), a0);
        a1 = fmaf(m2, __shfl(a1, shsrc, 64), a1);
        a2 = fmaf(m2, __shfl(a2, shsrc, 64), a2);
        a3 = fmaf(m2, __shfl(a3, shsrc, 64), a3);

        float gi = sigf(a0), gf = sigf(a1), gg = tanhfst(a2), go = sigf(a3);
        c = fmaf(gf, c, gi * gg);
        h = go * tanhfst(c);

        if (lane < 40) hcur[hslot] = h;
        if (isl2 && s > t0) h2out[(s - 1 - t0) * HIDN + h2col] = h;

        __syncthreads();
    }

    {
        const float4v* wp4 = (const float4v*)w_p;
        float4v p0 = wp4[0], p1 = wp4[1], p2 = wp4[2], p3 = wp4[3], p4 = wp4[4];
        const float bp = b_p[0];
        for (int tt = lane; tt < V0CHUNK; tt += 64) {
            const float4v* hr = (const float4v*)(h2out + tt * HIDN);
            float4v s_ = p0 * hr[0];
            s_ += p1 * hr[1]; s_ += p2 * hr[2]; s_ += p3 * hr[3]; s_ += p4 * hr[4];
            out[t0 + tt] = hsum4(s_) + bp;
        }
    }
}

extern "C" void kernel_launch(void* const* d_in, const int* in_sizes, int n_in,
                              void* d_out, int out_size, void* d_ws, size_t ws_size,
                              hipStream_t stream) {
    const float* x     = (const float*)d_in[0];
    const float* w_ih1 = (const float*)d_in[1];
    const float* w_hh1 = (const float*)d_in[2];
    const float* b1    = (const float*)d_in[3];
    const float* w_ih2 = (const float*)d_in[4];
    const float* w_hh2 = (const float*)d_in[5];
    const float* b2    = (const float*)d_in[6];
    const float* w_p   = (const float*)d_in[7];
    const float* b_p   = (const float*)d_in[8];
    float* out = (float*)d_out;

    if (ws_size >= XG_BYTES && d_ws != nullptr) {
        float4v* xg = (float4v*)d_ws;
        xproj<<<XP_BLOCKS, 256, 0, stream>>>(x, w_ih1, b1, xg);
        lstm_scan2<<<NBLK, 64, 0, stream>>>(xg, w_hh1, w_ih2, w_hh2, b2,
                                            w_p, b_p, out);
    } else {
        // workspace too small for xg: previous-generation fused kernel
        lstm_scan_v0<<<V0NBLK, 64, 0, stream>>>(x, w_ih1, w_hh1, b1,
                                                w_ih2, w_hh2, b2, w_p, b_p, out);
    }
}

// Round 4
// 177.069 us; speedup vs baseline: 1.2834x; 1.1379x over previous
//
#include <hip/hip_runtime.h>
#include <math.h>

#define T_TOTAL 262144
#define HIDN 20
#define IND 9

// ---- scan geometry: CHUNK per wave, 4 waves (chunks) per 256-thread block
#define CHUNK 64
#define WARM 32
#define NCHUNK (T_TOTAL / CHUNK)        // 4096 chunks (one per wave)
#define WAVES_PER_BLK 4
#define NWG (NCHUNK / WAVES_PER_BLK)    // 1024 workgroups -> 4/CU x 4 waves = 16 waves/CU

// xg workspace: [T][20] float4 (gates i,f,g,o per unit), bias b1 folded in
#define XG_BYTES ((size_t)T_TOTAL * 4 * HIDN * sizeof(float))   // 83.9 MB

typedef float float4v __attribute__((ext_vector_type(4)));
typedef float float2v __attribute__((ext_vector_type(2)));

__device__ __forceinline__ float fexp(float x) {
    return __builtin_amdgcn_exp2f(x * 1.44269504088896340736f);
}
__device__ __forceinline__ float sigf(float x) {
    return __builtin_amdgcn_rcpf(1.0f + fexp(-x));
}
__device__ __forceinline__ float tanhfst(float x) {
    return 1.0f - 2.0f * __builtin_amdgcn_rcpf(1.0f + fexp(2.0f * x));
}
__device__ __forceinline__ float hsum4(float4v a) {
    return (a.x + a.y) + (a.z + a.w);
}

#define LO2(a) __builtin_shufflevector(a, a, 0, 1)
#define HI2(a) __builtin_shufflevector(a, a, 2, 3)

// intra-wave LDS ordering fence (per-wave lgkmcnt; no s_barrier -> the xg
// prefetch queue [vmcnt] is never drained by the step loop)
#define LDS_FENCE() asm volatile("s_waitcnt lgkmcnt(0)" ::: "memory")

// ============================================================================
// Kernel 1: xg[t][k] = b1 + W_ih1 . x[t]  (recurrence-independent precompute).
// ============================================================================
#define XP_OUTS  (T_TOTAL * HIDN)     // 5242880
#define XP_HALF  (XP_OUTS / 2)        // 2621440  (divisible by HIDN)
#define XP_BLOCKS (XP_HALF / 256)     // 10240

__global__ __launch_bounds__(256)
void xproj(const float* __restrict__ x, const float* __restrict__ w_ih1,
           const float* __restrict__ b1, float4v* __restrict__ xg)
{
    __shared__ float wsm[4 * HIDN * IND + 4 * HIDN];   // 720 w + 80 b
    const int tid = threadIdx.x;
    for (int i = tid; i < 4 * HIDN * IND; i += 256) wsm[i] = w_ih1[i];
    for (int i = tid; i < 4 * HIDN; i += 256) wsm[4 * HIDN * IND + i] = b1[i];
    __syncthreads();

    const unsigned i0 = blockIdx.x * 256 + tid;
    const unsigned i1 = i0 + XP_HALF;                  // same k, t + 131072
    const unsigned t0 = i0 / HIDN;
    const int k = (int)(i0 - t0 * HIDN);
    const unsigned t1 = t0 + (XP_HALF / HIDN);

    const float* xr0 = x + (size_t)t0 * IND;
    const float* xr1 = x + (size_t)t1 * IND;
    float xa[IND], xb[IND];
#pragma unroll
    for (int d = 0; d < IND; ++d) { xa[d] = xr0[d]; xb[d] = xr1[d]; }

    float4v r0, r1;
#pragma unroll
    for (int q = 0; q < 4; ++q) {
        const float* wr = &wsm[(q * HIDN + k) * IND];
        const float bb = wsm[4 * HIDN * IND + q * HIDN + k];
        float a0 = bb, a1 = bb;
#pragma unroll
        for (int d = 0; d < IND; ++d) {
            const float w = wr[d];
            a0 = fmaf(w, xa[d], a0);
            a1 = fmaf(w, xb[d], a1);
        }
        r0[q] = a0; r1[q] = a1;
    }
    xg[i0] = r0;
    xg[i1] = r1;
}

// ============================================================================
// Kernel 2: recurrent scan, 4 independent chunk-waves per 256-thread block
// (private LDS slice per wave, no barriers). Lane roles within each wave:
//   0-19  layer1 unit k (xg supplies the input projection)
//   20-39 layer2 W_ih2 half (state owner)
//   40-59 layer2 W_hh2 half
//   60-63 idle (zero weights)
// xg stream: hand-unrolled x2 with two named prefetch registers -> each
// global load has a 2-step in-flight window (vmcnt(1) waits, never drained).
// Bias + xg are folded into the packed-dot accumulator init (off the
// post-dot critical path).
// ============================================================================
#define DECLW2(q) float4v wv##q##0, wv##q##1, wv##q##2, wv##q##3, wv##q##4; float bq##q;
#define LOADW2(q) { \
    const float4v* wr = (const float4v*)(wbase + ((q) * HIDN + krow) * HIDN); \
    wv##q##0 = scale * wr[0]; wv##q##1 = scale * wr[1]; wv##q##2 = scale * wr[2]; \
    wv##q##3 = scale * wr[3]; wv##q##4 = scale * wr[4]; \
    bq##q = (grp == 1) ? b2[(q) * HIDN + k] : 0.0f; \
}

#define PKCHUNK(j) { \
    float4v v = vb4[j]; \
    float2v vl = LO2(v), vh = HI2(v); \
    p0 = __builtin_elementwise_fma(LO2(wv0##j), vl, p0); \
    r0 = __builtin_elementwise_fma(HI2(wv0##j), vh, r0); \
    p1 = __builtin_elementwise_fma(LO2(wv1##j), vl, p1); \
    r1 = __builtin_elementwise_fma(HI2(wv1##j), vh, r1); \
    p2 = __builtin_elementwise_fma(LO2(wv2##j), vl, p2); \
    r2 = __builtin_elementwise_fma(HI2(wv2##j), vh, r2); \
    p3 = __builtin_elementwise_fma(LO2(wv3##j), vl, p3); \
    r3 = __builtin_elementwise_fma(HI2(wv3##j), vh, r3); \
}

// one LSTM step for row `scur` consuming prefetched xg register `xgv`
#define LSTEP(xgv, scur) { \
    float2v p0 = {fmaf(m1, (xgv).x, bq0), 0.0f}, r0 = (float2v)0.0f; \
    float2v p1 = {fmaf(m1, (xgv).y, bq1), 0.0f}, r1 = (float2v)0.0f; \
    float2v p2 = {fmaf(m1, (xgv).z, bq2), 0.0f}, r2 = (float2v)0.0f; \
    float2v p3 = {fmaf(m1, (xgv).w, bq3), 0.0f}, r3 = (float2v)0.0f; \
    PKCHUNK(0) PKCHUNK(1) PKCHUNK(2) PKCHUNK(3) PKCHUNK(4) \
    float2v u0 = p0 + r0, u1 = p1 + r1, u2 = p2 + r2, u3 = p3 + r3; \
    float a0 = u0.x + u0.y, a1 = u1.x + u1.y; \
    float a2 = u2.x + u2.y, a3 = u3.x + u3.y; \
    a0 = fmaf(m2, __shfl(a0, shsrc, 64), a0); \
    a1 = fmaf(m2, __shfl(a1, shsrc, 64), a1); \
    a2 = fmaf(m2, __shfl(a2, shsrc, 64), a2); \
    a3 = fmaf(m2, __shfl(a3, shsrc, 64), a3); \
    float gi = sigf(a0), gf = sigf(a1), gg = tanhfst(a2), go = sigf(a3); \
    c = fmaf(gf, c, gi * gg); \
    h = go * tanhfst(c); \
    if (lane < 40) hc[hslot] = h; \
    if (isl2 && (scur) > t0) h2o[((scur) - 1 - t0) * HIDN + h2col] = h; \
    LDS_FENCE(); \
}

__device__ __forceinline__ float4v ldrow(const float4v* __restrict__ xg,
                                         int t, int krow) {
    const int rw = (t < T_TOTAL) ? t : (T_TOTAL - 1);   // uniform -> SALU
    return xg[(size_t)rw * HIDN + krow];
}

__global__ __launch_bounds__(256)
void lstm_scan3(const float4v* __restrict__ xg,
                const float* __restrict__ w_hh1,
                const float* __restrict__ w_ih2, const float* __restrict__ w_hh2,
                const float* __restrict__ b2,
                const float* __restrict__ w_p, const float* __restrict__ b_p,
                float* __restrict__ out)
{
    __shared__ __align__(16) float hcur[WAVES_PER_BLK * 64];
    __shared__ __align__(16) float h2out[WAVES_PER_BLK * CHUNK * HIDN];

    const int tid  = threadIdx.x;
    const int wid  = tid >> 6;
    const int lane = tid & 63;
    float* hc  = hcur  + wid * 64;
    float* h2o = h2out + wid * (CHUNK * HIDN);

    const int chunk_id = blockIdx.x * WAVES_PER_BLK + wid;
    const int t0    = chunk_id * CHUNK;
    const int start = (t0 >= WARM) ? (t0 - WARM) : 0;
    const int endt  = t0 + CHUNK;
    // main-loop step count endt-start is 96 (or 64 for chunk 0) -> even

    hc[lane] = 0.0f;

    const int grp  = lane / 20;
    const int k    = lane - grp * 20;
    const int krow = (grp < 3) ? k : 0;
    const float scale = (grp < 3) ? 1.0f : 0.0f;
    const float* wbase = (grp == 1) ? w_ih2 : ((grp == 2) ? w_hh2 : w_hh1);

    DECLW2(0) DECLW2(1) DECLW2(2) DECLW2(3)
    LOADW2(0) LOADW2(1) LOADW2(2) LOADW2(3)

    const float4v* vb4 = (const float4v*)((lane < 40) ? hc : (hc + 32));
    const bool  isl2   = (lane >= 20 && lane < 40);
    const float m2     = isl2 ? 1.0f : 0.0f;
    const float m1     = (grp == 0) ? 1.0f : 0.0f;   // only L1 lanes add xg
    const int   h2col  = lane - 20;
    const int   hslot  = (lane < 20) ? lane : (32 + h2col);
    const int   shsrc  = (lane + 20) & 63;

    float4v x0 = ldrow(xg, start, krow);
    float4v nA = ldrow(xg, start + 1, krow);
    float4v nB = ldrow(xg, start + 2, krow);

    float c = 0.0f, h = 0.0f;

    // ---- peeled first step (s == start): h,c zero -> gates are xg/bias only
    {
        float a0 = fmaf(m1, x0.x, bq0);
        float a2 = fmaf(m1, x0.z, bq2);
        float a3 = fmaf(m1, x0.w, bq3);
        float gi = sigf(a0), gg = tanhfst(a2), go = sigf(a3);
        float cn = gi * gg;
        float hn = go * tanhfst(cn);
        c = (lane < 20) ? cn : 0.0f;
        h = (lane < 20) ? hn : 0.0f;
        if (lane < 40) hc[hslot] = h;   // layer-2 slots stay 0
        LDS_FENCE();
    }

    // ---- main loop, hand-unrolled x2 (step count is even)
    for (int s = start + 1; s <= endt; s += 2) {
        float4v xa_ = nA;
        nA = ldrow(xg, s + 2, krow);      // 2-step in-flight window
        LSTEP(xa_, s)
        float4v xb_ = nB;
        nB = ldrow(xg, s + 3, krow);
        LSTEP(xb_, s + 1)
    }

    // ---- projection epilogue: out[t] = w_p . h2[t] + b_p  (one t per lane)
    {
        const float4v* wp4 = (const float4v*)w_p;
        float4v q0 = wp4[0], q1 = wp4[1], q2 = wp4[2], q3 = wp4[3], q4 = wp4[4];
        const float bp = b_p[0];
        for (int tt = lane; tt < CHUNK; tt += 64) {
            const float4v* hr = (const float4v*)(h2o + tt * HIDN);
            float4v s_ = q0 * hr[0];
            s_ += q1 * hr[1]; s_ += q2 * hr[2]; s_ += q3 * hr[3]; s_ += q4 * hr[4];
            out[t0 + tt] = hsum4(s_) + bp;
        }
    }
}

// ============================================================================
// Fallback (round-0 kernel, verbatim): used only if ws_size is too small for
// the xg workspace.
// ============================================================================
#define V0CHUNK 128
#define V0WARM 48
#define V0MAXST (V0WARM + V0CHUNK + 1)
#define V0NBLK (T_TOTAL / V0CHUNK)

#define DECLW(q) \
    float4v w0v##q##0, w0v##q##1, w0v##q##2, w0v##q##3, w0v##q##4; \
    float4v w0x##q##0, w0x##q##1; float w0x##q##8; float b0q##q;

#define LOADW(q) { \
    const float4v* wr = (const float4v*)(wbase + ((q) * HIDN + krow) * HIDN); \
    w0v##q##0 = scale * wr[0]; w0v##q##1 = scale * wr[1]; w0v##q##2 = scale * wr[2]; \
    w0v##q##3 = scale * wr[3]; w0v##q##4 = scale * wr[4]; \
    w0x##q##0 = (float4v)0.0f; w0x##q##1 = (float4v)0.0f; w0x##q##8 = 0.0f; \
    if (grp == 0) { \
        const float* r = w_ih1 + ((q) * HIDN + k) * IND; \
        w0x##q##0 = (float4v){r[0], r[1], r[2], r[3]}; \
        w0x##q##1 = (float4v){r[4], r[5], r[6], r[7]}; \
        w0x##q##8 = r[8]; \
    } \
    b0q##q = (grp == 0) ? b1[(q) * HIDN + k] : ((grp == 1) ? b2[(q) * HIDN + k] : 0.0f); \
}

#define GATE(q) ({ \
    float4v s_ = w0v##q##0 * v0; \
    s_ += w0v##q##1 * v1; s_ += w0v##q##2 * v2; \
    s_ += w0v##q##3 * v3; s_ += w0v##q##4 * v4; \
    s_ += w0x##q##0 * xv0; s_ += w0x##q##1 * xv1; \
    hsum4(s_) + fmaf(w0x##q##8, xv8, b0q##q); })

#define GATEX(q) ({ \
    float4v s_ = w0x##q##0 * xv0 + w0x##q##1 * xv1; \
    hsum4(s_) + fmaf(w0x##q##8, xv8, b0q##q); })

__global__ __launch_bounds__(64)
void lstm_scan_v0(const float* __restrict__ x,
                  const float* __restrict__ w_ih1, const float* __restrict__ w_hh1,
                  const float* __restrict__ b1,
                  const float* __restrict__ w_ih2, const float* __restrict__ w_hh2,
                  const float* __restrict__ b2,
                  const float* __restrict__ w_p, const float* __restrict__ b_p,
                  float* __restrict__ out)
{
    __shared__ __align__(16) float xbuf[V0MAXST * 12];
    __shared__ __align__(16) float hcur[64];
    __shared__ __align__(16) float h2out[V0CHUNK * HIDN];

    const int lane = threadIdx.x;
    const int blk  = blockIdx.x;
    const int t0   = blk * V0CHUNK;
    const int start = (t0 >= V0WARM) ? (t0 - V0WARM) : 0;
    const int endt  = t0 + V0CHUNK;
    const int nst   = endt - start + 1;

    for (int idx = lane; idx < nst * IND; idx += 64) {
        int stp = idx / IND, d = idx - stp * IND;
        int gt = start + stp; if (gt > T_TOTAL - 1) gt = T_TOTAL - 1;
        xbuf[stp * 12 + d] = x[gt * IND + d];
    }
    hcur[lane] = 0.0f;

    const int grp  = lane / 20;
    const int k    = lane - grp * 20;
    const int krow = (grp < 3) ? k : 0;
    const float scale = (grp < 3) ? 1.0f : 0.0f;
    const float* wbase = (grp == 1) ? w_ih2 : ((grp == 2) ? w_hh2 : w_hh1);

    DECLW(0) DECLW(1) DECLW(2) DECLW(3)
    LOADW(0) LOADW(1) LOADW(2) LOADW(3)

    const float* vbase = (lane < 40) ? hcur : (hcur + 32);
    const bool  isl2   = (lane >= 20 && lane < 40);
    const float m2     = isl2 ? 1.0f : 0.0f;
    const int   h2col  = lane - 20;
    const int   hslot  = (lane < 20) ? lane : (32 + h2col);
    const int   shsrc  = (lane + 20) & 63;

    __syncthreads();

    float c = 0.0f, h = 0.0f;

    {
        const float* xr = &xbuf[0];
        float4v xv0 = *(const float4v*)xr, xv1 = *(const float4v*)(xr + 4);
        float xv8 = xr[8];
        float a0 = GATEX(0), a1 = GATEX(1), a2 = GATEX(2), a3 = GATEX(3);
        float gi = sigf(a0), gg = tanhfst(a2), go = sigf(a3);
        (void)a1;
        float cn = gi * gg;
        float hn = go * tanhfst(cn);
        c = (lane < 20) ? cn : 0.0f;
        h = (lane < 20) ? hn : 0.0f;
        if (lane < 40) hcur[hslot] = h;
        __syncthreads();
    }

    for (int s = start + 1; s <= endt; ++s) {
        const float4v* vb4 = (const float4v*)vbase;
        float4v v0 = vb4[0], v1 = vb4[1], v2 = vb4[2], v3 = vb4[3], v4 = vb4[4];

        const float* xr = &xbuf[(s - start) * 12];
        float4v xv0 = *(const float4v*)xr, xv1 = *(const float4v*)(xr + 4);
        float xv8 = xr[8];

        float a0 = GATE(0), a1 = GATE(1), a2 = GATE(2), a3 = GATE(3);

        a0 = fmaf(m2, __shfl(a0, shsrc, 64), a0);
        a1 = fmaf(m2, __shfl(a1, shsrc, 64), a1);
        a2 = fmaf(m2, __shfl(a2, shsrc, 64), a2);
        a3 = fmaf(m2, __shfl(a3, shsrc, 64), a3);

        float gi = sigf(a0), gf = sigf(a1), gg = tanhfst(a2), go = sigf(a3);
        c = fmaf(gf, c, gi * gg);
        h = go * tanhfst(c);

        if (lane < 40) hcur[hslot] = h;
        if (isl2 && s > t0) h2out[(s - 1 - t0) * HIDN + h2col] = h;

        __syncthreads();
    }

    {
        const float4v* wp4 = (const float4v*)w_p;
        float4v p0 = wp4[0], p1 = wp4[1], p2 = wp4[2], p3 = wp4[3], p4 = wp4[4];
        const float bp = b_p[0];
        for (int tt = lane; tt < V0CHUNK; tt += 64) {
            const float4v* hr = (const float4v*)(h2out + tt * HIDN);
            float4v s_ = p0 * hr[0];
            s_ += p1 * hr[1]; s_ += p2 * hr[2]; s_ += p3 * hr[3]; s_ += p4 * hr[4];
            out[t0 + tt] = hsum4(s_) + bp;
        }
    }
}

extern "C" void kernel_launch(void* const* d_in, const int* in_sizes, int n_in,
                              void* d_out, int out_size, void* d_ws, size_t ws_size,
                              hipStream_t stream) {
    const float* x     = (const float*)d_in[0];
    const float* w_ih1 = (const float*)d_in[1];
    const float* w_hh1 = (const float*)d_in[2];
    const float* b1    = (const float*)d_in[3];
    const float* w_ih2 = (const float*)d_in[4];
    const float* w_hh2 = (const float*)d_in[5];
    const float* b2    = (const float*)d_in[6];
    const float* w_p   = (const float*)d_in[7];
    const float* b_p   = (const float*)d_in[8];
    float* out = (float*)d_out;

    if (ws_size >= XG_BYTES && d_ws != nullptr) {
        float4v* xg = (float4v*)d_ws;
        xproj<<<XP_BLOCKS, 256, 0, stream>>>(x, w_ih1, b1, xg);
        lstm_scan3<<<NWG, 256, 0, stream>>>(xg, w_hh1, w_ih2, w_hh2, b2,
                                            w_p, b_p, out);
    } else {
        // workspace too small for xg: previous-generation fused kernel
        lstm_scan_v0<<<V0NBLK, 64, 0, stream>>>(x, w_ih1, w_hh1, b1,
                                                w_ih2, w_hh2, b2, w_p, b_p, out);
    }
}